// Round 2
// baseline (142.680 us; speedup 1.0000x reference)
//
#include <hip/hip_runtime.h>
#include <hip/hip_bf16.h>
#include <stdint.h>

typedef float f32x4 __attribute__((ext_vector_type(4)));
typedef float f32x4v __attribute__((ext_vector_type(4)));
typedef short short8 __attribute__((ext_vector_type(8)));
typedef unsigned short u16;
typedef unsigned short u16x8 __attribute__((ext_vector_type(8)));
typedef unsigned short u16x4 __attribute__((ext_vector_type(4)));

#define MFMA16x16x32 __builtin_amdgcn_mfma_f32_16x16x32_bf16

__device__ __forceinline__ u16 f2bf(float f) {
    unsigned int u = __builtin_bit_cast(unsigned int, f);
    u += 0x7fffu + ((u >> 16) & 1u);
    return (u16)(u >> 16);
}

// ---------------------------------------------------------------------------
// Kernel 0: W [1024,128] f32  ->  WT [3][128][1024] bf16 (transposed)
// ---------------------------------------------------------------------------
__global__ void k_transpose_w(const float* __restrict__ Wq, const float* __restrict__ Wk,
                              const float* __restrict__ Wv, u16* __restrict__ WT) {
    int tid = blockIdx.x * 256 + threadIdx.x;  // 0..49151
    int w   = tid >> 14;                       // 0..2
    int rem = tid & 16383;
    int n   = rem >> 7;                        // 0..127
    int kc  = rem & 127;                       // 0..127, 8 k-values each
    const float* W = (w == 0) ? Wq : ((w == 1) ? Wk : Wv);
    u16x8 v;
#pragma unroll
    for (int j = 0; j < 8; ++j)
        v[j] = f2bf(W[(size_t)(kc * 8 + j) * 128 + n]);
    *(u16x8*)(&WT[((size_t)w << 17) + (size_t)n * 1024 + kc * 8]) = v;
}

// ---------------------------------------------------------------------------
// Kernel 1: QKV projection GEMM (unchanged this round).
// ---------------------------------------------------------------------------
__global__ __launch_bounds__(256) void k_qkv_gemm(
    const float* __restrict__ x, const u16* __restrict__ WT,
    u16* __restrict__ qb, u16* __restrict__ kb, u16* __restrict__ vT)
{
    __shared__ u16 la[128 * 64];
    __shared__ u16 lb[128 * 64];
    const int tid  = threadIdx.x;
    const int m0   = blockIdx.x * 128;
    const int w    = blockIdx.y;              // 0=q, 1=k, 2=v
    const int lane = tid & 63;
    const int wid  = tid >> 6;
    const int wr = wid >> 1, wc = wid & 1;
    const int lrow = lane & 15, lk = lane >> 4;
    const u16* wt = WT + ((size_t)w << 17);

    f32x4 acc[4][4];
#pragma unroll
    for (int i = 0; i < 4; ++i)
#pragma unroll
        for (int j = 0; j < 4; ++j) acc[i][j] = (f32x4){0.f, 0.f, 0.f, 0.f};

    for (int kt = 0; kt < 16; ++kt) {
        __syncthreads();
#pragma unroll
        for (int i = 0; i < 4; ++i) {
            int g = tid + i * 256;            // 0..1023
            int row = g >> 3, kg = g & 7;
            const float* src = x + (size_t)(m0 + row) * 1024 + kt * 64 + kg * 8;
            f32x4v f0 = *(const f32x4v*)src;
            f32x4v f1 = *(const f32x4v*)(src + 4);
            u16x8 v;
            v[0] = f2bf(f0[0]); v[1] = f2bf(f0[1]); v[2] = f2bf(f0[2]); v[3] = f2bf(f0[3]);
            v[4] = f2bf(f1[0]); v[5] = f2bf(f1[1]); v[6] = f2bf(f1[2]); v[7] = f2bf(f1[3]);
            *(u16x8*)(&la[row * 64 + ((kg ^ (row & 7)) << 3)]) = v;
        }
#pragma unroll
        for (int i = 0; i < 4; ++i) {
            int g = tid + i * 256;
            int row = g >> 3, kg = g & 7;
            u16x8 v = *(const u16x8*)(wt + (size_t)row * 1024 + kt * 64 + kg * 8);
            *(u16x8*)(&lb[row * 64 + ((kg ^ (row & 7)) << 3)]) = v;
        }
        __syncthreads();
#pragma unroll
        for (int ks = 0; ks < 2; ++ks) {
            short8 af[4], bfr[4];
#pragma unroll
            for (int mf = 0; mf < 4; ++mf) {
                int row = wr * 64 + mf * 16 + lrow;
                int blk = (ks * 4 + lk) ^ (row & 7);
                af[mf] = *(const short8*)(&la[row * 64 + (blk << 3)]);
            }
#pragma unroll
            for (int nf = 0; nf < 4; ++nf) {
                int row = wc * 64 + nf * 16 + lrow;
                int blk = (ks * 4 + lk) ^ (row & 7);
                bfr[nf] = *(const short8*)(&lb[row * 64 + (blk << 3)]);
            }
#pragma unroll
            for (int mf = 0; mf < 4; ++mf)
#pragma unroll
                for (int nf = 0; nf < 4; ++nf)
                    acc[mf][nf] = MFMA16x16x32(af[mf], bfr[nf], acc[mf][nf], 0, 0, 0);
        }
    }
    if (w < 2) {
        u16* dst = (w == 0) ? qb : kb;
#pragma unroll
        for (int mf = 0; mf < 4; ++mf) {
            int row0 = m0 + wr * 64 + mf * 16 + lk * 4;
#pragma unroll
            for (int nf = 0; nf < 4; ++nf) {
                int col = wc * 64 + nf * 16 + lrow;
#pragma unroll
                for (int jj = 0; jj < 4; ++jj)
                    dst[(size_t)(row0 + jj) * 128 + col] = f2bf(acc[mf][nf][jj]);
            }
        }
    } else {
#pragma unroll
        for (int mf = 0; mf < 4; ++mf) {
            int row0 = m0 + wr * 64 + mf * 16 + lk * 4;
            int bb = row0 >> 11, t0 = row0 & 2047;
#pragma unroll
            for (int nf = 0; nf < 4; ++nf) {
                int col = wc * 64 + nf * 16 + lrow;
                u16x4 v;
#pragma unroll
                for (int jj = 0; jj < 4; ++jj) v[jj] = f2bf(acc[mf][nf][jj]);
                *(u16x4*)(&vT[((size_t)bb * 128 + col) * 2048 + t0]) = v;
            }
        }
    }
}

// ---------------------------------------------------------------------------
// Kernel 2 (v2): causal flash attention, KV-split across waves.
// Grid: 1024 blocks 1D; b = id&7 (XCD-pins one batch per L2), qi = 127-(id>>3).
// Block = 16 q-rows. Wave w handles kv tiles t = w, w+4, ... (tile = 64 kv).
// No LDS staging of K/V (L2-resident); no __syncthreads in main loop.
// Per-wave partial (O,m,l) combined through LDS at the end.
// ---------------------------------------------------------------------------
__global__ __launch_bounds__(256, 4) void k_flash2(
    const u16* __restrict__ qb, const u16* __restrict__ kb, const u16* __restrict__ vT,
    float* __restrict__ out)
{
    __shared__ float o_sh[4][16][128];   // per-wave O partial; first 2KB of each
                                         // wave's slab doubles as its P buffer
    __shared__ float m_sh[4][16];
    __shared__ float l_sh[4][16];

    const int tid  = threadIdx.x;
    const int lane = tid & 63, wid = tid >> 6;
    const int lrow = lane & 15, lk = lane >> 4;
    const int b     = blockIdx.x & 7;
    const int qi    = 127 - (int)(blockIdx.x >> 3);
    const int qrow0 = qi * 16;
    const int ntiles = (qrow0 + 16 + 63) >> 6;

    // Q A-fragments: row = lrow, k = ks*32 + lk*8
    short8 qf[4];
    {
        const u16* qp = qb + ((size_t)b * 2048 + qrow0 + lrow) * 128;
#pragma unroll
        for (int ks = 0; ks < 4; ++ks) qf[ks] = *(const short8*)(qp + ks * 32 + lk * 8);
    }

    f32x4 of[8];
#pragma unroll
    for (int i = 0; i < 8; ++i) of[i] = (f32x4){0.f, 0.f, 0.f, 0.f};
    float mrun[4], lsum[4];
#pragma unroll
    for (int j = 0; j < 4; ++j) { mrun[j] = -1e30f; lsum[j] = 0.f; }

    const u16* kbase = kb + (size_t)b * 2048 * 128;
    const u16* vbase = vT + (size_t)b * 128 * 2048;
    u16* pw = (u16*)&o_sh[wid][0][0];    // 16x64 u16 = 2KB, union with O slab

    for (int t = wid; t < ntiles; t += 4) {
        const int kv0 = t << 6;
        // ---- S = Q K^T (B-frags direct from L2) ----
        f32x4 sf[4];
#pragma unroll
        for (int nf = 0; nf < 4; ++nf) sf[nf] = (f32x4){0.f, 0.f, 0.f, 0.f};
#pragma unroll
        for (int ks = 0; ks < 4; ++ks) {
            short8 kf[4];
#pragma unroll
            for (int nf = 0; nf < 4; ++nf)
                kf[nf] = *(const short8*)(kbase + (size_t)(kv0 + nf * 16 + lrow) * 128 + ks * 32 + lk * 8);
#pragma unroll
            for (int nf = 0; nf < 4; ++nf)
                sf[nf] = MFMA16x16x32(qf[ks], kf[nf], sf[nf], 0, 0, 0);
        }
        // ---- scale + causal mask ----
        const bool needmask = (kv0 + 63 > qrow0);
#pragma unroll
        for (int nf = 0; nf < 4; ++nf)
#pragma unroll
            for (int jj = 0; jj < 4; ++jj) {
                float s = sf[nf][jj] * 0.03125f;   // C^-0.5 = 1/32
                if (needmask && (kv0 + nf * 16 + lrow > qrow0 + lk * 4 + jj)) s = -1e30f;
                sf[nf][jj] = s;
            }
        // ---- online softmax (16-lane groups) ----
        float mt[4];
#pragma unroll
        for (int jj = 0; jj < 4; ++jj)
            mt[jj] = fmaxf(fmaxf(sf[0][jj], sf[1][jj]), fmaxf(sf[2][jj], sf[3][jj]));
#pragma unroll
        for (int off = 1; off < 16; off <<= 1)
#pragma unroll
            for (int jj = 0; jj < 4; ++jj)
                mt[jj] = fmaxf(mt[jj], __shfl_xor(mt[jj], off));
        bool small = true;
#pragma unroll
        for (int jj = 0; jj < 4; ++jj) small = small && (mt[jj] <= mrun[jj] + 8.f);
        if (!__all(small)) {
#pragma unroll
            for (int jj = 0; jj < 4; ++jj) {
                float mnew = fmaxf(mrun[jj], mt[jj]);
                float sc   = __expf(mrun[jj] - mnew);
                mrun[jj]   = mnew;
                lsum[jj]  *= sc;
#pragma unroll
                for (int df = 0; df < 8; ++df) of[df][jj] *= sc;
            }
        }
        float rs[4] = {0.f, 0.f, 0.f, 0.f};
#pragma unroll
        for (int nf = 0; nf < 4; ++nf)
#pragma unroll
            for (int jj = 0; jj < 4; ++jj) {
                float e = __expf(sf[nf][jj] - mrun[jj]);
                sf[nf][jj] = e;
                rs[jj] += e;
            }
#pragma unroll
        for (int off = 1; off < 16; off <<= 1)
#pragma unroll
            for (int jj = 0; jj < 4; ++jj)
                rs[jj] += __shfl_xor(rs[jj], off);
#pragma unroll
        for (int jj = 0; jj < 4; ++jj) lsum[jj] += rs[jj];

        // ---- P -> per-wave LDS (bf16, swizzled), then A-frags ----
#pragma unroll
        for (int nf = 0; nf < 4; ++nf)
#pragma unroll
            for (int jj = 0; jj < 4; ++jj) {
                int row = lk * 4 + jj;
                int col = nf * 16 + lrow;
                pw[row * 64 + (((col >> 3) ^ (row & 7)) << 3) + (col & 7)] = f2bf(sf[nf][jj]);
            }
        asm volatile("s_waitcnt lgkmcnt(0)" ::: "memory");
        __builtin_amdgcn_sched_barrier(0);
        short8 paf[2];
#pragma unroll
        for (int ks2 = 0; ks2 < 2; ++ks2) {
            int blk = (ks2 * 4 + lk) ^ (lrow & 7);
            paf[ks2] = *(const short8*)(&pw[lrow * 64 + (blk << 3)]);
        }
        // ---- PV (V^T frags direct from L2) ----
        __builtin_amdgcn_s_setprio(1);
#pragma unroll
        for (int ks2 = 0; ks2 < 2; ++ks2)
#pragma unroll
            for (int df = 0; df < 8; ++df) {
                short8 vf = *(const short8*)(vbase + (size_t)(df * 16 + lrow) * 2048 + kv0 + ks2 * 32 + lk * 8);
                of[df] = MFMA16x16x32(paf[ks2], vf, of[df], 0, 0, 0);
            }
        __builtin_amdgcn_s_setprio(0);
    }

    // ---- block combine of 4 wave-partials ----
    // (pw region is dead now; overwrite wave's own slab)
#pragma unroll
    for (int df = 0; df < 8; ++df)
#pragma unroll
        for (int jj = 0; jj < 4; ++jj)
            o_sh[wid][lk * 4 + jj][df * 16 + lrow] = of[df][jj];
    if (lrow == 0) {
#pragma unroll
        for (int jj = 0; jj < 4; ++jj) {
            m_sh[wid][lk * 4 + jj] = mrun[jj];
            l_sh[wid][lk * 4 + jj] = lsum[jj];
        }
    }
    __syncthreads();

    const int r  = tid >> 4;
    const int c0 = (tid & 15) * 8;
    float mw[4];
#pragma unroll
    for (int w = 0; w < 4; ++w) mw[w] = m_sh[w][r];
    float M = fmaxf(fmaxf(mw[0], mw[1]), fmaxf(mw[2], mw[3]));
    float wgt[4], den = 0.f;
#pragma unroll
    for (int w = 0; w < 4; ++w) {
        wgt[w] = __expf(mw[w] - M);
        den += wgt[w] * l_sh[w][r];
    }
    float acc8[8];
#pragma unroll
    for (int j = 0; j < 8; ++j) acc8[j] = 0.f;
#pragma unroll
    for (int w = 0; w < 4; ++w) {
        f32x4 a = *(const f32x4*)(&o_sh[w][r][c0]);
        f32x4 c = *(const f32x4*)(&o_sh[w][r][c0 + 4]);
#pragma unroll
        for (int j = 0; j < 4; ++j) { acc8[j] += wgt[w] * a[j]; acc8[4 + j] += wgt[w] * c[j]; }
    }
    float inv = 1.f / den;
    float* op = out + ((size_t)b * 2048 + qrow0 + r) * 128 + c0;
#pragma unroll
    for (int j = 0; j < 8; ++j) op[j] = acc8[j] * inv;
}

// ---------------------------------------------------------------------------
extern "C" void kernel_launch(void* const* d_in, const int* in_sizes, int n_in,
                              void* d_out, int out_size, void* d_ws, size_t ws_size,
                              hipStream_t stream) {
    const float* x  = (const float*)d_in[0];
    const float* Wq = (const float*)d_in[1];
    const float* Wk = (const float*)d_in[2];
    const float* Wv = (const float*)d_in[3];
    float* out = (float*)d_out;

    u16* ws = (u16*)d_ws;
    u16* qb = ws;                                  // [8*2048][128] bf16
    u16* kb = ws + (size_t)16384 * 128;            // [8*2048][128] bf16
    u16* vT = ws + (size_t)2 * 16384 * 128;        // [8][128][2048] bf16
    u16* WT = ws + (size_t)3 * 16384 * 128;        // [3][128][1024] bf16

    k_transpose_w<<<192, 256, 0, stream>>>(Wq, Wk, Wv, WT);
    k_qkv_gemm<<<dim3(128, 3), 256, 0, stream>>>(x, WT, qb, kb, vT);
    k_flash2<<<1024, 256, 0, stream>>>(qb, kb, vT, out);
}

// Round 3
// 108.750 us; speedup vs baseline: 1.3120x; 1.3120x over previous
//
#include <hip/hip_runtime.h>
#include <hip/hip_bf16.h>
#include <stdint.h>

typedef float f32x4 __attribute__((ext_vector_type(4)));
typedef float f32x4v __attribute__((ext_vector_type(4)));
typedef short short8 __attribute__((ext_vector_type(8)));
typedef unsigned short u16;
typedef unsigned short u16x8 __attribute__((ext_vector_type(8)));
typedef unsigned short u16x4 __attribute__((ext_vector_type(4)));

#define MFMA16x16x32 __builtin_amdgcn_mfma_f32_16x16x32_bf16

__device__ __forceinline__ u16 f2bf(float f) {
    unsigned int u = __builtin_bit_cast(unsigned int, f);
    u += 0x7fffu + ((u >> 16) & 1u);
    return (u16)(u >> 16);
}

// ---------------------------------------------------------------------------
// Kernel 0: W [1024,128] f32  ->  WT [3][128][1024] bf16 (transposed)
// ---------------------------------------------------------------------------
__global__ void k_transpose_w(const float* __restrict__ Wq, const float* __restrict__ Wk,
                              const float* __restrict__ Wv, u16* __restrict__ WT) {
    int tid = blockIdx.x * 256 + threadIdx.x;  // 0..49151
    int w   = tid >> 14;                       // 0..2
    int rem = tid & 16383;
    int n   = rem >> 7;                        // 0..127
    int kc  = rem & 127;                       // 0..127, 8 k-values each
    const float* W = (w == 0) ? Wq : ((w == 1) ? Wk : Wv);
    u16x8 v;
#pragma unroll
    for (int j = 0; j < 8; ++j)
        v[j] = f2bf(W[(size_t)(kc * 8 + j) * 128 + n]);
    *(u16x8*)(&WT[((size_t)w << 17) + (size_t)n * 1024 + kc * 8]) = v;
}

// ---------------------------------------------------------------------------
// Kernel 1: QKV projection GEMM (unchanged this round).
// ---------------------------------------------------------------------------
__global__ __launch_bounds__(256) void k_qkv_gemm(
    const float* __restrict__ x, const u16* __restrict__ WT,
    u16* __restrict__ qb, u16* __restrict__ kb, u16* __restrict__ vT)
{
    __shared__ u16 la[128 * 64];
    __shared__ u16 lb[128 * 64];
    const int tid  = threadIdx.x;
    const int m0   = blockIdx.x * 128;
    const int w    = blockIdx.y;              // 0=q, 1=k, 2=v
    const int lane = tid & 63;
    const int wid  = tid >> 6;
    const int wr = wid >> 1, wc = wid & 1;
    const int lrow = lane & 15, lk = lane >> 4;
    const u16* wt = WT + ((size_t)w << 17);

    f32x4 acc[4][4];
#pragma unroll
    for (int i = 0; i < 4; ++i)
#pragma unroll
        for (int j = 0; j < 4; ++j) acc[i][j] = (f32x4){0.f, 0.f, 0.f, 0.f};

    for (int kt = 0; kt < 16; ++kt) {
        __syncthreads();
#pragma unroll
        for (int i = 0; i < 4; ++i) {
            int g = tid + i * 256;            // 0..1023
            int row = g >> 3, kg = g & 7;
            const float* src = x + (size_t)(m0 + row) * 1024 + kt * 64 + kg * 8;
            f32x4v f0 = *(const f32x4v*)src;
            f32x4v f1 = *(const f32x4v*)(src + 4);
            u16x8 v;
            v[0] = f2bf(f0[0]); v[1] = f2bf(f0[1]); v[2] = f2bf(f0[2]); v[3] = f2bf(f0[3]);
            v[4] = f2bf(f1[0]); v[5] = f2bf(f1[1]); v[6] = f2bf(f1[2]); v[7] = f2bf(f1[3]);
            *(u16x8*)(&la[row * 64 + ((kg ^ (row & 7)) << 3)]) = v;
        }
#pragma unroll
        for (int i = 0; i < 4; ++i) {
            int g = tid + i * 256;
            int row = g >> 3, kg = g & 7;
            u16x8 v = *(const u16x8*)(wt + (size_t)row * 1024 + kt * 64 + kg * 8);
            *(u16x8*)(&lb[row * 64 + ((kg ^ (row & 7)) << 3)]) = v;
        }
        __syncthreads();
#pragma unroll
        for (int ks = 0; ks < 2; ++ks) {
            short8 af[4], bfr[4];
#pragma unroll
            for (int mf = 0; mf < 4; ++mf) {
                int row = wr * 64 + mf * 16 + lrow;
                int blk = (ks * 4 + lk) ^ (row & 7);
                af[mf] = *(const short8*)(&la[row * 64 + (blk << 3)]);
            }
#pragma unroll
            for (int nf = 0; nf < 4; ++nf) {
                int row = wc * 64 + nf * 16 + lrow;
                int blk = (ks * 4 + lk) ^ (row & 7);
                bfr[nf] = *(const short8*)(&lb[row * 64 + (blk << 3)]);
            }
#pragma unroll
            for (int mf = 0; mf < 4; ++mf)
#pragma unroll
                for (int nf = 0; nf < 4; ++nf)
                    acc[mf][nf] = MFMA16x16x32(af[mf], bfr[nf], acc[mf][nf], 0, 0, 0);
        }
    }
    if (w < 2) {
        u16* dst = (w == 0) ? qb : kb;
#pragma unroll
        for (int mf = 0; mf < 4; ++mf) {
            int row0 = m0 + wr * 64 + mf * 16 + lk * 4;
#pragma unroll
            for (int nf = 0; nf < 4; ++nf) {
                int col = wc * 64 + nf * 16 + lrow;
#pragma unroll
                for (int jj = 0; jj < 4; ++jj)
                    dst[(size_t)(row0 + jj) * 128 + col] = f2bf(acc[mf][nf][jj]);
            }
        }
    } else {
#pragma unroll
        for (int mf = 0; mf < 4; ++mf) {
            int row0 = m0 + wr * 64 + mf * 16 + lk * 4;
            int bb = row0 >> 11, t0 = row0 & 2047;
#pragma unroll
            for (int nf = 0; nf < 4; ++nf) {
                int col = wc * 64 + nf * 16 + lrow;
                u16x4 v;
#pragma unroll
                for (int jj = 0; jj < 4; ++jj) v[jj] = f2bf(acc[mf][nf][jj]);
                *(u16x4*)(&vT[((size_t)bb * 128 + col) * 2048 + t0]) = v;
            }
        }
    }
}

// ---------------------------------------------------------------------------
// Kernel 2 (v3): same structure as v2, but NO min-waves launch bound.
// v2 post-mortem: __launch_bounds__(256,4) capped VGPR at 64 -> massive
// scratch spill (WRITE_SIZE 46MB vs 8.4MB output). LDS (32.5KB) already
// pins occupancy at 4 blocks/CU, so the VGPR cap bought nothing.
// ---------------------------------------------------------------------------
__global__ __launch_bounds__(256) void k_flash2(
    const u16* __restrict__ qb, const u16* __restrict__ kb, const u16* __restrict__ vT,
    float* __restrict__ out)
{
    __shared__ float o_sh[4][16][128];   // per-wave O partial; first 2KB of each
                                         // wave's slab doubles as its P buffer
    __shared__ float m_sh[4][16];
    __shared__ float l_sh[4][16];

    const int tid  = threadIdx.x;
    const int lane = tid & 63, wid = tid >> 6;
    const int lrow = lane & 15, lk = lane >> 4;
    const int b     = blockIdx.x & 7;
    const int qi    = 127 - (int)(blockIdx.x >> 3);
    const int qrow0 = qi * 16;
    const int ntiles = (qrow0 + 16 + 63) >> 6;

    // Q A-fragments: row = lrow, k = ks*32 + lk*8
    short8 qf[4];
    {
        const u16* qp = qb + ((size_t)b * 2048 + qrow0 + lrow) * 128;
#pragma unroll
        for (int ks = 0; ks < 4; ++ks) qf[ks] = *(const short8*)(qp + ks * 32 + lk * 8);
    }

    f32x4 of[8];
#pragma unroll
    for (int i = 0; i < 8; ++i) of[i] = (f32x4){0.f, 0.f, 0.f, 0.f};
    float mrun[4], lsum[4];
#pragma unroll
    for (int j = 0; j < 4; ++j) { mrun[j] = -1e30f; lsum[j] = 0.f; }

    const u16* kbase = kb + (size_t)b * 2048 * 128;
    const u16* vbase = vT + (size_t)b * 128 * 2048;
    u16* pw = (u16*)&o_sh[wid][0][0];    // 16x64 u16 = 2KB, union with O slab

    for (int t = wid; t < ntiles; t += 4) {
        const int kv0 = t << 6;
        // ---- S = Q K^T (B-frags direct from L2) ----
        f32x4 sf[4];
#pragma unroll
        for (int nf = 0; nf < 4; ++nf) sf[nf] = (f32x4){0.f, 0.f, 0.f, 0.f};
#pragma unroll
        for (int ks = 0; ks < 4; ++ks) {
            short8 kf[4];
#pragma unroll
            for (int nf = 0; nf < 4; ++nf)
                kf[nf] = *(const short8*)(kbase + (size_t)(kv0 + nf * 16 + lrow) * 128 + ks * 32 + lk * 8);
#pragma unroll
            for (int nf = 0; nf < 4; ++nf)
                sf[nf] = MFMA16x16x32(qf[ks], kf[nf], sf[nf], 0, 0, 0);
        }
        // ---- scale + causal mask ----
        const bool needmask = (kv0 + 63 > qrow0);
#pragma unroll
        for (int nf = 0; nf < 4; ++nf)
#pragma unroll
            for (int jj = 0; jj < 4; ++jj) {
                float s = sf[nf][jj] * 0.03125f;   // C^-0.5 = 1/32
                if (needmask && (kv0 + nf * 16 + lrow > qrow0 + lk * 4 + jj)) s = -1e30f;
                sf[nf][jj] = s;
            }
        // ---- online softmax (16-lane groups) ----
        float mt[4];
#pragma unroll
        for (int jj = 0; jj < 4; ++jj)
            mt[jj] = fmaxf(fmaxf(sf[0][jj], sf[1][jj]), fmaxf(sf[2][jj], sf[3][jj]));
#pragma unroll
        for (int off = 1; off < 16; off <<= 1)
#pragma unroll
            for (int jj = 0; jj < 4; ++jj)
                mt[jj] = fmaxf(mt[jj], __shfl_xor(mt[jj], off));
        bool small = true;
#pragma unroll
        for (int jj = 0; jj < 4; ++jj) small = small && (mt[jj] <= mrun[jj] + 8.f);
        if (!__all(small)) {
#pragma unroll
            for (int jj = 0; jj < 4; ++jj) {
                float mnew = fmaxf(mrun[jj], mt[jj]);
                float sc   = __expf(mrun[jj] - mnew);
                mrun[jj]   = mnew;
                lsum[jj]  *= sc;
#pragma unroll
                for (int df = 0; df < 8; ++df) of[df][jj] *= sc;
            }
        }
        float rs[4] = {0.f, 0.f, 0.f, 0.f};
#pragma unroll
        for (int nf = 0; nf < 4; ++nf)
#pragma unroll
            for (int jj = 0; jj < 4; ++jj) {
                float e = __expf(sf[nf][jj] - mrun[jj]);
                sf[nf][jj] = e;
                rs[jj] += e;
            }
#pragma unroll
        for (int off = 1; off < 16; off <<= 1)
#pragma unroll
            for (int jj = 0; jj < 4; ++jj)
                rs[jj] += __shfl_xor(rs[jj], off);
#pragma unroll
        for (int jj = 0; jj < 4; ++jj) lsum[jj] += rs[jj];

        // ---- P -> per-wave LDS (bf16, swizzled), then A-frags ----
#pragma unroll
        for (int nf = 0; nf < 4; ++nf)
#pragma unroll
            for (int jj = 0; jj < 4; ++jj) {
                int row = lk * 4 + jj;
                int col = nf * 16 + lrow;
                pw[row * 64 + (((col >> 3) ^ (row & 7)) << 3) + (col & 7)] = f2bf(sf[nf][jj]);
            }
        asm volatile("s_waitcnt lgkmcnt(0)" ::: "memory");
        __builtin_amdgcn_sched_barrier(0);
        short8 paf[2];
#pragma unroll
        for (int ks2 = 0; ks2 < 2; ++ks2) {
            int blk = (ks2 * 4 + lk) ^ (lrow & 7);
            paf[ks2] = *(const short8*)(&pw[lrow * 64 + (blk << 3)]);
        }
        // ---- PV (V^T frags direct from L2) ----
        __builtin_amdgcn_s_setprio(1);
#pragma unroll
        for (int ks2 = 0; ks2 < 2; ++ks2)
#pragma unroll
            for (int df = 0; df < 8; ++df) {
                short8 vf = *(const short8*)(vbase + (size_t)(df * 16 + lrow) * 2048 + kv0 + ks2 * 32 + lk * 8);
                of[df] = MFMA16x16x32(paf[ks2], vf, of[df], 0, 0, 0);
            }
        __builtin_amdgcn_s_setprio(0);
    }

    // ---- block combine of 4 wave-partials ----
#pragma unroll
    for (int df = 0; df < 8; ++df)
#pragma unroll
        for (int jj = 0; jj < 4; ++jj)
            o_sh[wid][lk * 4 + jj][df * 16 + lrow] = of[df][jj];
    if (lrow == 0) {
#pragma unroll
        for (int jj = 0; jj < 4; ++jj) {
            m_sh[wid][lk * 4 + jj] = mrun[jj];
            l_sh[wid][lk * 4 + jj] = lsum[jj];
        }
    }
    __syncthreads();

    const int r  = tid >> 4;
    const int c0 = (tid & 15) * 8;
    float mw[4];
#pragma unroll
    for (int w = 0; w < 4; ++w) mw[w] = m_sh[w][r];
    float M = fmaxf(fmaxf(mw[0], mw[1]), fmaxf(mw[2], mw[3]));
    float wgt[4], den = 0.f;
#pragma unroll
    for (int w = 0; w < 4; ++w) {
        wgt[w] = __expf(mw[w] - M);
        den += wgt[w] * l_sh[w][r];
    }
    float acc8[8];
#pragma unroll
    for (int j = 0; j < 8; ++j) acc8[j] = 0.f;
#pragma unroll
    for (int w = 0; w < 4; ++w) {
        f32x4 a = *(const f32x4*)(&o_sh[w][r][c0]);
        f32x4 c = *(const f32x4*)(&o_sh[w][r][c0 + 4]);
#pragma unroll
        for (int j = 0; j < 4; ++j) { acc8[j] += wgt[w] * a[j]; acc8[4 + j] += wgt[w] * c[j]; }
    }
    float inv = 1.f / den;
    float* op = out + ((size_t)b * 2048 + qrow0 + r) * 128 + c0;
#pragma unroll
    for (int j = 0; j < 8; ++j) op[j] = acc8[j] * inv;
}

// ---------------------------------------------------------------------------
extern "C" void kernel_launch(void* const* d_in, const int* in_sizes, int n_in,
                              void* d_out, int out_size, void* d_ws, size_t ws_size,
                              hipStream_t stream) {
    const float* x  = (const float*)d_in[0];
    const float* Wq = (const float*)d_in[1];
    const float* Wk = (const float*)d_in[2];
    const float* Wv = (const float*)d_in[3];
    float* out = (float*)d_out;

    u16* ws = (u16*)d_ws;
    u16* qb = ws;                                  // [8*2048][128] bf16
    u16* kb = ws + (size_t)16384 * 128;            // [8*2048][128] bf16
    u16* vT = ws + (size_t)2 * 16384 * 128;        // [8][128][2048] bf16
    u16* WT = ws + (size_t)3 * 16384 * 128;        // [3][128][1024] bf16

    k_transpose_w<<<192, 256, 0, stream>>>(Wq, Wk, Wv, WT);
    k_qkv_gemm<<<dim3(128, 3), 256, 0, stream>>>(x, WT, qb, kb, vT);
    k_flash2<<<1024, 256, 0, stream>>>(qb, kb, vT, out);
}